// Round 1
// baseline (479.652 us; speedup 1.0000x reference)
//
#include <hip/hip_runtime.h>

// Problem constants (setup_inputs: B=8, E=50000, D=128, N=10000)
#define B 8
#define E 50000
#define D 128
#define NSEG 10000
#define OUTD (5 * D)

#define FLT_MAX_F 3.402823466e+38f

// ws layout (4-byte elements):
//   [0,      80000)   counts   (int,   B*NSEG)
//   [80000,  81024)   colsum   (float, B*D)
//   [81024, 161024)   offsets  (int,   B*NSEG)
//   [161024,241024)   cursor   (int,   B*NSEG)
//   [241024,641024)   perm     (int,   B*E)

__global__ void hist_kernel(const int* __restrict__ idx, int* __restrict__ counts) {
    int t = blockIdx.x * 256 + threadIdx.x;
    if (t >= B * E) return;
    int b = t / E;
    atomicAdd(&counts[b * NSEG + idx[t]], 1);
}

// One block per batch: exclusive scan of counts -> offsets (and cursor copy).
__global__ void scan_kernel(const int* __restrict__ counts, int* __restrict__ offsets,
                            int* __restrict__ cursor) {
    int b = blockIdx.x;
    __shared__ int wsum[16];
    __shared__ int s_carry;
    if (threadIdx.x == 0) s_carry = 0;
    __syncthreads();
    int wid = threadIdx.x >> 6;
    int lane = threadIdx.x & 63;
    for (int base = 0; base < NSEG; base += 1024) {
        int i = base + threadIdx.x;
        int v = (i < NSEG) ? counts[b * NSEG + i] : 0;
        int x = v;  // inclusive wave scan
        #pragma unroll
        for (int off = 1; off < 64; off <<= 1) {
            int t = __shfl_up(x, off, 64);
            if (lane >= off) x += t;
        }
        if (lane == 63) wsum[wid] = x;
        __syncthreads();
        int carry = s_carry;
        __syncthreads();
        if (threadIdx.x == 0) {
            int acc = 0;
            #pragma unroll
            for (int k = 0; k < 16; ++k) { int t = wsum[k]; wsum[k] = acc; acc += t; }
            s_carry = carry + acc;
        }
        __syncthreads();
        int excl = carry + wsum[wid] + x - v;
        if (i < NSEG) {
            offsets[b * NSEG + i] = excl;
            cursor[b * NSEG + i] = excl;
        }
        __syncthreads();
    }
}

__global__ void scatter_kernel(const int* __restrict__ idx, int* __restrict__ cursor,
                               int* __restrict__ perm) {
    int t = blockIdx.x * 256 + threadIdx.x;
    if (t >= B * E) return;
    int b = t / E;
    int e = t - b * E;
    int pos = atomicAdd(&cursor[b * NSEG + idx[t]], 1);
    perm[b * E + pos] = e;
}

// One wave (64 lanes) per (b, n). Lane l owns features 2l, 2l+1 (float2).
// Writes: sum | max | mean | sumsq(temp, becomes var) | softmax
__global__ void agg_kernel(const float* __restrict__ data, const float* __restrict__ beta_p,
                           const int* __restrict__ counts, const int* __restrict__ offsets,
                           const int* __restrict__ perm, float* __restrict__ out) {
    int w = (blockIdx.x * 256 + threadIdx.x) >> 6;  // w = b*NSEG + n
    int lane = threadIdx.x & 63;
    if (w >= B * NSEG) return;
    int b = w / NSEG;
    int cnt = counts[w];
    int off = offsets[w];
    float beta = *beta_p;

    float s0 = 0.f, s1 = 0.f;                    // sum
    float q0 = 0.f, q1 = 0.f;                    // sum of squares
    float m0 = -FLT_MAX_F, m1 = -FLT_MAX_F;      // max
    float es0 = 0.f, es1 = 0.f;                  // sum exp(beta*d)
    float ws0 = 0.f, ws1 = 0.f;                  // sum d*exp(beta*d)

    const int* pp = perm + b * E + off;
    const float* dbase = data + (size_t)b * E * D;
    for (int j = 0; j < cnt; ++j) {
        int e = pp[j];
        float2 v = ((const float2*)(dbase + (size_t)e * D))[lane];
        s0 += v.x; s1 += v.y;
        q0 = fmaf(v.x, v.x, q0); q1 = fmaf(v.y, v.y, q1);
        m0 = fmaxf(m0, v.x); m1 = fmaxf(m1, v.y);
        float ex0 = expf(beta * v.x);
        float ex1 = expf(beta * v.y);
        es0 += ex0; es1 += ex1;
        ws0 = fmaf(v.x, ex0, ws0); ws1 = fmaf(v.y, ex1, ws1);
    }

    float cc = fmaxf((float)cnt, 1.0f);
    float mean0 = s0 / cc, mean1 = s1 / cc;
    float mx0 = cnt ? m0 : 0.f, mx1 = cnt ? m1 : 0.f;
    float sf0 = cnt ? ws0 / es0 : 0.f, sf1 = cnt ? ws1 / es1 : 0.f;

    float* o = out + (size_t)w * OUTD;
    ((float2*)(o        ))[lane] = make_float2(s0, s1);
    ((float2*)(o +     D))[lane] = make_float2(mx0, mx1);
    ((float2*)(o + 2 * D))[lane] = make_float2(mean0, mean1);
    ((float2*)(o + 3 * D))[lane] = make_float2(q0, q1);     // sumsq, finalized by var_kernel
    ((float2*)(o + 4 * D))[lane] = make_float2(sf0, sf1);
}

// Reduce the ssum slot over n -> colsum[b][d]  (for d_mean = colsum/E)
#define K5_CHUNK 100
__global__ void colsum_kernel(const float* __restrict__ out, float* __restrict__ colsum) {
    int chunks = NSEG / K5_CHUNK;  // 100
    int b = blockIdx.x / chunks;
    int n0 = (blockIdx.x % chunks) * K5_CHUNK;
    int d = threadIdx.x & 127;
    int half = threadIdx.x >> 7;  // 0/1 -> two rows in flight
    float partial = 0.f;
    for (int r = half; r < K5_CHUNK; r += 2) {
        partial += out[(size_t)(b * NSEG + n0 + r) * OUTD + d];
    }
    atomicAdd(&colsum[b * D + d], partial);
}

// var = relu( q/cc - 2*dm*mean + (c/cc)*dm^2 ), in-place over the sumsq slot.
__global__ void var_kernel(const float* __restrict__ colsum, const int* __restrict__ counts,
                           float* __restrict__ out) {
    int t = blockIdx.x * 256 + threadIdx.x;
    if (t >= B * NSEG * 64) return;
    int w = t >> 6;
    int lane = t & 63;
    int b = w / NSEG;
    int cnt = counts[w];
    float c = (float)cnt;
    float cc = fmaxf(c, 1.0f);
    float frac = c / cc;  // 1 if nonempty else 0
    float* o = out + (size_t)w * OUTD;
    float2 q = ((const float2*)(o + 3 * D))[lane];
    float2 mn = ((const float2*)(o + 2 * D))[lane];
    const float invE = 1.0f / (float)E;
    float dm0 = colsum[b * D + 2 * lane] * invE;
    float dm1 = colsum[b * D + 2 * lane + 1] * invE;
    float v0 = q.x / cc - 2.f * dm0 * mn.x + frac * dm0 * dm0;
    float v1 = q.y / cc - 2.f * dm1 * mn.y + frac * dm1 * dm1;
    ((float2*)(o + 3 * D))[lane] = make_float2(fmaxf(v0, 0.f), fmaxf(v1, 0.f));
}

extern "C" void kernel_launch(void* const* d_in, const int* in_sizes, int n_in,
                              void* d_out, int out_size, void* d_ws, size_t ws_size,
                              hipStream_t stream) {
    const float* data = (const float*)d_in[0];
    const float* beta = (const float*)d_in[1];
    const int* indices = (const int*)d_in[2];
    float* out = (float*)d_out;

    int* counts   = (int*)d_ws;
    float* colsum = (float*)d_ws + 80000;
    int* offsets  = (int*)d_ws + 81024;
    int* cursor   = (int*)d_ws + 161024;
    int* perm     = (int*)d_ws + 241024;

    // zero counts + colsum (ws is re-poisoned to 0xAA before every launch)
    hipMemsetAsync(d_ws, 0, (size_t)(80000 + 1024) * 4, stream);

    hist_kernel<<<(B * E + 255) / 256, 256, 0, stream>>>(indices, counts);
    scan_kernel<<<B, 1024, 0, stream>>>(counts, offsets, cursor);
    scatter_kernel<<<(B * E + 255) / 256, 256, 0, stream>>>(indices, cursor, perm);
    agg_kernel<<<(B * NSEG * 64) / 256, 256, 0, stream>>>(data, beta, counts, offsets, perm, out);
    colsum_kernel<<<B * (NSEG / K5_CHUNK), 256, 0, stream>>>(out, colsum);
    var_kernel<<<(B * NSEG * 64) / 256, 256, 0, stream>>>(colsum, counts, out);
}

// Round 3
// 455.774 us; speedup vs baseline: 1.0524x; 1.0524x over previous
//
#include <hip/hip_runtime.h>

// Problem constants (setup_inputs: B=8, E=50000, D=128, N=10000)
#define B 8
#define E 50000
#define D 128
#define NSEG 10000
#define OUTD (5 * D)

#define FLT_MAX_F 3.402823466e+38f
#define LOG2E 1.4426950408889634f

// ws layout (4-byte elements):
//   [0,      80000)   counts   (int,   B*NSEG)
//   [80000,  81024)   colsum   (float, B*D)
//   [81024, 161024)   cursor   (int,   B*NSEG)   scan result; scatter bumps; agg: off=cursor-cnt
//   [161024,561024)   perm     (int,   B*E)

// Fused: histogram of indices + column-sum of data (colsum[b][d] = sum_e data[b,e,d],
// valid because every element belongs to exactly one segment).
#define HC_BLOCKS_PER_B 128
__global__ void hist_colsum_kernel(const float* __restrict__ data, const int* __restrict__ idx,
                                   int* __restrict__ counts, float* __restrict__ colsum) {
    int b = blockIdx.x / HC_BLOCKS_PER_B;
    int chunk = blockIdx.x % HC_BLOCKS_PER_B;
    const int per = (E + HC_BLOCKS_PER_B - 1) / HC_BLOCKS_PER_B;  // 391
    int r0 = chunk * per;
    int r1 = min(E, r0 + per);

    // histogram (coalesced idx reads, ~5-way avg atomic contention)
    for (int r = r0 + (int)threadIdx.x; r < r1; r += 256)
        atomicAdd(&counts[b * NSEG + idx[b * E + r]], 1);

    // column sum: one wave per row, lane l owns features 2l, 2l+1
    int wid = threadIdx.x >> 6, lane = threadIdx.x & 63;
    float c0 = 0.f, c1 = 0.f;
    const float* dbase = data + (size_t)b * E * D;
    for (int r = r0 + wid; r < r1; r += 4) {
        float2 v = ((const float2*)(dbase + (size_t)r * D))[lane];
        c0 += v.x; c1 += v.y;
    }
    __shared__ float red[4][128];
    red[wid][2 * lane] = c0;
    red[wid][2 * lane + 1] = c1;
    __syncthreads();
    if (wid == 0) {
        float t0 = red[0][2 * lane] + red[1][2 * lane] + red[2][2 * lane] + red[3][2 * lane];
        float t1 = red[0][2 * lane + 1] + red[1][2 * lane + 1] + red[2][2 * lane + 1] + red[3][2 * lane + 1];
        atomicAdd(&colsum[b * D + 2 * lane], t0);        // 128 blocks/batch -> 128-way, fine
        atomicAdd(&colsum[b * D + 2 * lane + 1], t1);
    }
}

// One block per batch: exclusive scan of counts -> cursor.
__global__ void scan_kernel(const int* __restrict__ counts, int* __restrict__ cursor) {
    int b = blockIdx.x;
    __shared__ int wsum[16];
    __shared__ int s_carry;
    if (threadIdx.x == 0) s_carry = 0;
    __syncthreads();
    int wid = threadIdx.x >> 6;
    int lane = threadIdx.x & 63;
    for (int base = 0; base < NSEG; base += 1024) {
        int i = base + threadIdx.x;
        int v = (i < NSEG) ? counts[b * NSEG + i] : 0;
        int x = v;  // inclusive wave scan
        #pragma unroll
        for (int off = 1; off < 64; off <<= 1) {
            int t = __shfl_up(x, off, 64);
            if (lane >= off) x += t;
        }
        if (lane == 63) wsum[wid] = x;
        __syncthreads();
        int carry = s_carry;
        __syncthreads();
        if (threadIdx.x == 0) {
            int acc = 0;
            #pragma unroll
            for (int k = 0; k < 16; ++k) { int t = wsum[k]; wsum[k] = acc; acc += t; }
            s_carry = carry + acc;
        }
        __syncthreads();
        int excl = carry + wsum[wid] + x - v;
        if (i < NSEG) cursor[b * NSEG + i] = excl;
        __syncthreads();
    }
}

__global__ void scatter_kernel(const int* __restrict__ idx, int* __restrict__ cursor,
                               int* __restrict__ perm) {
    int t = blockIdx.x * 256 + threadIdx.x;
    if (t >= B * E) return;
    int b = t / E;
    int e = t - b * E;
    int pos = atomicAdd(&cursor[b * NSEG + idx[t]], 1);
    perm[b * E + pos] = e;
}

// One wave per (b, n). Lane l owns features 2l, 2l+1 (float2).
// Cooperative perm load + 8-deep gather prefetch (uniform-branch guarded, so no
// redundant gathers for the common cnt~5 case). Var finalized in-register.
// Writes: sum | max | mean | var | softmax  -- out written exactly once.
__global__ __launch_bounds__(256) void agg_kernel(
        const float* __restrict__ data, const float* __restrict__ beta_p,
        const int* __restrict__ counts, const int* __restrict__ cursor,
        const int* __restrict__ perm, const float* __restrict__ colsum,
        float* __restrict__ out) {
    int w = (blockIdx.x * 256 + threadIdx.x) >> 6;  // w = b*NSEG + n
    int lane = threadIdx.x & 63;
    if (w >= B * NSEG) return;
    int b = w / NSEG;
    int cnt = counts[w];
    int off = cursor[w] - cnt;  // cursor was bumped by cnt during scatter
    float k2 = beta_p[0] * LOG2E;  // exp(beta*x) = 2^(k2*x); |beta*x| <~ 6, always in range

    float s0 = 0.f, s1 = 0.f;                    // sum
    float q0 = 0.f, q1 = 0.f;                    // sum of squares
    float m0 = -FLT_MAX_F, m1 = -FLT_MAX_F;      // max
    float es0 = 0.f, es1 = 0.f;                  // sum exp(beta*d)
    float ws0 = 0.f, ws1 = 0.f;                  // sum d*exp(beta*d)

    const int* pp = perm + b * E + off;
    const float* dbase = data + (size_t)b * E * D;

    for (int base = 0; base < cnt; base += 64) {
        int rem = cnt - base;
        int m = rem < 64 ? rem : 64;
        int el = (lane < m) ? pp[base + lane] : 0;  // one coalesced perm load per 64 elems
        for (int j0 = 0; j0 < m; j0 += 8) {
            float2 v[8];
            #pragma unroll
            for (int k = 0; k < 8; ++k) {           // up to 8 independent 512B gathers in flight
                int j = j0 + k;                     // j,m wave-uniform -> uniform branch
                if (j < m) {
                    int ej = __shfl(el, j, 64);
                    v[k] = ((const float2*)(dbase + (size_t)ej * D))[lane];
                }
            }
            #pragma unroll
            for (int k = 0; k < 8; ++k) {
                if (j0 + k < m) {
                    float2 x = v[k];
                    s0 += x.x; s1 += x.y;
                    q0 = fmaf(x.x, x.x, q0); q1 = fmaf(x.y, x.y, q1);
                    m0 = fmaxf(m0, x.x); m1 = fmaxf(m1, x.y);
                    float e0 = __builtin_amdgcn_exp2f(k2 * x.x);
                    float e1 = __builtin_amdgcn_exp2f(k2 * x.y);
                    es0 += e0; es1 += e1;
                    ws0 = fmaf(x.x, e0, ws0); ws1 = fmaf(x.y, e1, ws1);
                }
            }
        }
    }

    float c = (float)cnt;
    float cc = fmaxf(c, 1.0f);
    float inv = 1.0f / cc;
    float mean0 = s0 * inv, mean1 = s1 * inv;
    float mx0 = cnt ? m0 : 0.f, mx1 = cnt ? m1 : 0.f;
    float sf0 = cnt ? ws0 / es0 : 0.f, sf1 = cnt ? ws1 / es1 : 0.f;

    const float invE = 1.0f / (float)E;
    float dm0 = colsum[b * D + 2 * lane] * invE;     // per-batch feature mean (4KB, L2-hot)
    float dm1 = colsum[b * D + 2 * lane + 1] * invE;
    float frac = c * inv;  // 1 if nonempty else 0
    float v0 = fmaxf(q0 * inv - 2.f * dm0 * mean0 + frac * dm0 * dm0, 0.f);
    float v1 = fmaxf(q1 * inv - 2.f * dm1 * mean1 + frac * dm1 * dm1, 0.f);

    float* o = out + (size_t)w * OUTD;
    ((float2*)(o        ))[lane] = make_float2(s0, s1);
    ((float2*)(o +     D))[lane] = make_float2(mx0, mx1);
    ((float2*)(o + 2 * D))[lane] = make_float2(mean0, mean1);
    ((float2*)(o + 3 * D))[lane] = make_float2(v0, v1);
    ((float2*)(o + 4 * D))[lane] = make_float2(sf0, sf1);
}

extern "C" void kernel_launch(void* const* d_in, const int* in_sizes, int n_in,
                              void* d_out, int out_size, void* d_ws, size_t ws_size,
                              hipStream_t stream) {
    const float* data = (const float*)d_in[0];
    const float* beta = (const float*)d_in[1];
    const int* indices = (const int*)d_in[2];
    float* out = (float*)d_out;

    int* counts   = (int*)d_ws;
    float* colsum = (float*)d_ws + 80000;
    int* cursor   = (int*)d_ws + 81024;
    int* perm     = (int*)d_ws + 161024;

    // zero counts + colsum (ws is re-poisoned to 0xAA before every launch)
    hipMemsetAsync(d_ws, 0, (size_t)(80000 + 1024) * 4, stream);

    hist_colsum_kernel<<<B * HC_BLOCKS_PER_B, 256, 0, stream>>>(data, indices, counts, colsum);
    scan_kernel<<<B, 1024, 0, stream>>>(counts, cursor);
    scatter_kernel<<<(B * E + 255) / 256, 256, 0, stream>>>(indices, cursor, perm);
    agg_kernel<<<(B * NSEG * 64) / 256, 256, 0, stream>>>(data, beta, counts, cursor, perm,
                                                          colsum, out);
}